// Round 7
// baseline (270.261 us; speedup 1.0000x reference)
//
#include <hip/hip_runtime.h>

// ---------------------------------------------------------------------------
// GraphSAGE 2-layer forward, MI355X (gfx950)
//   h   = relu(mean_agg(x) @ W1l + b1 + x @ W1r)
//   out =      mean_agg(h) @ W2l + b2 + h @ W2r
// R7: spmm gather with wave-uniform scalar src addressing (readfirstlane ->
// SGPR base + saddr loads, dwordx4 csr reads); coarse_scatter caches dst in
// registers (single edge-list read). GEMM/fine-sort unchanged from R6.
// ---------------------------------------------------------------------------

typedef __attribute__((ext_vector_type(8))) short short8;
typedef __attribute__((ext_vector_type(4))) float floatx4;
typedef __attribute__((ext_vector_type(4))) unsigned short ushort4v;

#define BSH1 9                     // coarse bucket = 512 consecutive dst nodes
#define CHUNK 2048                 // edges per chunk (coarse scatter)
// packed pair: src in bits[0:23), dst&511 in bits[23:32). requires N < 2^23

__device__ inline unsigned short f2b(float f) {  // f32 -> bf16 (RNE)
    unsigned u = __builtin_bit_cast(unsigned, f);
    return (unsigned short)((u + 0x7FFFu + ((u >> 16) & 1u)) >> 16);
}
__device__ inline float blo(unsigned v) { return __builtin_bit_cast(float, v << 16); }
__device__ inline float bhi(unsigned v) { return __builtin_bit_cast(float, v & 0xffff0000u); }

// ---- edge layout detection (int64 vs int32 buffer) ------------------------
__global__ void detect_kernel(const int* __restrict__ e32, int nelem, int* flag) {
    __shared__ int bad;
    if (threadIdx.x == 0) bad = 0;
    __syncthreads();
    int half = nelem >> 1;  // = E
    int viol = 0;
    for (int i = threadIdx.x; i < 4096; i += blockDim.x) {
        long long k = ((long long)i * half) / 4096;
        if (e32[2 * k + 1] != 0) viol++;   // int64 => hi words all 0
    }
    if (viol) atomicAdd(&bad, viol);
    __syncthreads();
    if (threadIdx.x == 0) flag[0] = (bad == 0) ? 1 : 0;  // 1 = int64 layout
}

__device__ inline void decode_edge(const int* e32, bool is64, int E, int i, int& s, int& d) {
    if (is64) { s = e32[2 * (long long)i]; d = e32[2 * ((long long)E + i)]; }
    else      { s = e32[i];                d = e32[E + i]; }
}

// ---- coarse bucket count: LDS histogram per block, tiny global flush ------
__global__ __launch_bounds__(256) void coarse_count_kernel(const int* __restrict__ e32,
                                                           const int* __restrict__ flag,
                                                           int* __restrict__ bcnt,
                                                           int E, int nb1) {
    extern __shared__ int lh[];
    for (int i = threadIdx.x; i < nb1; i += blockDim.x) lh[i] = 0;
    __syncthreads();
    bool is64 = flag[0] != 0;
    int stride = gridDim.x * blockDim.x;
    for (int i = blockIdx.x * blockDim.x + threadIdx.x; i < E; i += stride) {
        int d = is64 ? e32[2 * ((long long)E + i)] : e32[E + i];
        atomicAdd(&lh[d >> BSH1], 1);
    }
    __syncthreads();
    for (int i = threadIdx.x; i < nb1; i += blockDim.x) {
        int c = lh[i];
        if (c) atomicAdd(&bcnt[i], c);
    }
}

// ---- exclusive scan (single block) ----------------------------------------
__global__ __launch_bounds__(1024) void scan_kernel(const int* __restrict__ deg,
                                                    int* __restrict__ off,
                                                    int* __restrict__ cursor, int N) {
    __shared__ int wsum[16];
    __shared__ int s_carry;
    int t = threadIdx.x;
    int lane = t & 63, w = t >> 6;
    if (t == 0) s_carry = 0;
    __syncthreads();
    for (int base = 0; base < N; base += 1024) {
        int i = base + t;
        int v = (i < N) ? deg[i] : 0;
        int sc = v;
        #pragma unroll
        for (int o = 1; o < 64; o <<= 1) {
            int u = __shfl_up(sc, o, 64);
            if (lane >= o) sc += u;
        }
        if (lane == 63) wsum[w] = sc;
        __syncthreads();
        int woff = 0;
        for (int j = 0; j < w; ++j) woff += wsum[j];
        int c = s_carry;
        int excl = c + woff + (sc - v);
        if (i < N) { off[i] = excl; cursor[i] = excl; }
        __syncthreads();
        if (t == 1023) s_carry = c + woff + sc;
        __syncthreads();
    }
    if (t == 0) off[N] = s_carry;
}

// ---- coarse scatter: dst cached in regs, one reservation per bucket -------
__global__ __launch_bounds__(256) void coarse_scatter_kernel(const int* __restrict__ e32,
                                                             const int* __restrict__ flag,
                                                             int* __restrict__ bcur,
                                                             unsigned* __restrict__ pairs,
                                                             int E, int nb1) {
    extern __shared__ int lh[];            // [nb1] cursor/hist + [nb1] base
    int t = threadIdx.x;
    bool is64 = flag[0] != 0;
    int nchunks = (E + CHUNK - 1) / CHUNK;
    for (int ch = blockIdx.x; ch < nchunks; ch += gridDim.x) {
        int e0 = ch * CHUNK;
        int e1 = min(e0 + CHUNK, E);
        for (int i = t; i < nb1; i += 256) lh[i] = 0;
        __syncthreads();
        int dreg[CHUNK / 256];
        #pragma unroll
        for (int j = 0; j < CHUNK / 256; ++j) {
            int i = e0 + j * 256 + t;
            int d = -1;
            if (i < e1) d = is64 ? e32[2 * ((long long)E + i)] : e32[E + i];
            dreg[j] = d;
            if (d >= 0) atomicAdd(&lh[d >> BSH1], 1);
        }
        __syncthreads();
        for (int i = t; i < nb1; i += 256) {
            int c = lh[i];
            lh[nb1 + i] = c ? atomicAdd(&bcur[i], c) : 0;   // global reservation
            lh[i] = 0;                                      // reuse as local cursor
        }
        __syncthreads();
        #pragma unroll
        for (int j = 0; j < CHUNK / 256; ++j) {
            int i = e0 + j * 256 + t;
            if (i < e1) {
                int s = is64 ? e32[2 * (long long)i] : e32[i];
                int d = dreg[j];
                int k = d >> BSH1;
                int r = atomicAdd(&lh[k], 1);
                pairs[lh[nb1 + k] + r] = (unsigned)s | ((unsigned)(d & ((1 << BSH1) - 1)) << 23);
            }
        }
        __syncthreads();
    }
}

// ---- fine CSR build: one block per coarse bucket (region L2-resident) -----
__global__ __launch_bounds__(256) void fine_csr_kernel(const unsigned* __restrict__ pairs,
                                                       const int* __restrict__ boff,
                                                       int* __restrict__ off,
                                                       int* __restrict__ csr,
                                                       int N, int nb1, int E) {
    __shared__ int ldeg[512], loff[512];
    __shared__ int wsum[4];
    int b = blockIdx.x;
    if (b >= nb1) return;
    int t = threadIdx.x;
    int p0 = boff[b], p1 = boff[b + 1];
    int base = b << BSH1;
    ldeg[2 * t] = 0; ldeg[2 * t + 1] = 0;
    __syncthreads();
    for (int i = p0 + t; i < p1; i += 256) atomicAdd(&ldeg[pairs[i] >> 23], 1);
    __syncthreads();
    // exclusive scan of 512 entries with 256 threads
    {
        int lane = t & 63, w = t >> 6;
        int v0 = ldeg[2 * t], v1 = ldeg[2 * t + 1];
        int v = v0 + v1, sc = v;
        #pragma unroll
        for (int o = 1; o < 64; o <<= 1) {
            int u = __shfl_up(sc, o, 64);
            if (lane >= o) sc += u;
        }
        if (lane == 63) wsum[w] = sc;
        __syncthreads();
        int cross = 0;
        for (int j = 0; j < w; ++j) cross += wsum[j];
        int ex = cross + sc - v;
        loff[2 * t] = ex;
        loff[2 * t + 1] = ex + v0;
        int d0 = base + 2 * t, d1 = d0 + 1;
        if (d0 < N) off[d0] = p0 + ex;
        if (d1 < N) off[d1] = p0 + ex + v0;
    }
    __syncthreads();
    ldeg[2 * t] = 0; ldeg[2 * t + 1] = 0;   // reuse as cursors
    __syncthreads();
    for (int i = p0 + t; i < p1; i += 256) {
        unsigned e = pairs[i];
        int dl = e >> 23;
        int r = atomicAdd(&ldeg[dl], 1);
        csr[p0 + loff[dl] + r] = (int)(e & 0x7FFFFFu);
    }
    if (b == 0 && t == 0) off[N] = E;
}

// ---- f32 -> bf16 table ----------------------------------------------------
__global__ void cvt_kernel(const float* __restrict__ in, unsigned short* __restrict__ out, int n4) {
    int stride = gridDim.x * blockDim.x;
    for (int i = blockIdx.x * blockDim.x + threadIdx.x; i < n4; i += stride) {
        float4 v = ((const float4*)in)[i];
        ushort4v o;
        o[0] = f2b(v.x); o[1] = f2b(v.y); o[2] = f2b(v.z); o[3] = f2b(v.w);
        ((ushort4v*)out)[i] = o;
    }
}

// ---- SpMM mean: gather rows of X, write bf16 mean -------------------------
// one wave per node; src index is wave-uniform -> force scalar (SGPR) row
// base via readfirstlane; csr stream read as aligned dwordx4.
template<int BF16IN>
__global__ __launch_bounds__(256) void spmm_mean_kernel(const void* __restrict__ Xv,
                                                        const int* __restrict__ off,
                                                        const int* __restrict__ csr,
                                                        unsigned* __restrict__ outb, int N) {
    int wid = blockIdx.x * 4 + (threadIdx.x >> 6);
    int lane = threadIdx.x & 63;
    if (wid >= N) return;
    int b0 = off[wid], b1 = off[wid + 1];
    float ax = 0.f, ay = 0.f;
    int i = b0;
    if (BF16IN) {
        const unsigned* X = (const unsigned*)Xv;   // row = 64 uints (128 bf16)
        // peel to 4-aligned csr index
        for (; i < b1 && (i & 3); ++i) {
            unsigned s = __builtin_amdgcn_readfirstlane((unsigned)csr[i]);
            unsigned v = X[((size_t)s << 6) + lane];
            ax += blo(v); ay += bhi(v);
        }
        for (; i + 7 < b1; i += 8) {
            int4 ca = *(const int4*)(csr + i);
            int4 cb = *(const int4*)(csr + i + 4);
            unsigned s0 = __builtin_amdgcn_readfirstlane((unsigned)ca.x);
            unsigned s1 = __builtin_amdgcn_readfirstlane((unsigned)ca.y);
            unsigned s2 = __builtin_amdgcn_readfirstlane((unsigned)ca.z);
            unsigned s3 = __builtin_amdgcn_readfirstlane((unsigned)ca.w);
            unsigned s4 = __builtin_amdgcn_readfirstlane((unsigned)cb.x);
            unsigned s5 = __builtin_amdgcn_readfirstlane((unsigned)cb.y);
            unsigned s6 = __builtin_amdgcn_readfirstlane((unsigned)cb.z);
            unsigned s7 = __builtin_amdgcn_readfirstlane((unsigned)cb.w);
            unsigned v0 = X[((size_t)s0 << 6) + lane];
            unsigned v1 = X[((size_t)s1 << 6) + lane];
            unsigned v2 = X[((size_t)s2 << 6) + lane];
            unsigned v3 = X[((size_t)s3 << 6) + lane];
            unsigned v4 = X[((size_t)s4 << 6) + lane];
            unsigned v5 = X[((size_t)s5 << 6) + lane];
            unsigned v6 = X[((size_t)s6 << 6) + lane];
            unsigned v7 = X[((size_t)s7 << 6) + lane];
            ax += (blo(v0) + blo(v1)) + (blo(v2) + blo(v3)) +
                  ((blo(v4) + blo(v5)) + (blo(v6) + blo(v7)));
            ay += (bhi(v0) + bhi(v1)) + (bhi(v2) + bhi(v3)) +
                  ((bhi(v4) + bhi(v5)) + (bhi(v6) + bhi(v7)));
        }
        for (; i + 3 < b1; i += 4) {
            int4 ca = *(const int4*)(csr + i);
            unsigned s0 = __builtin_amdgcn_readfirstlane((unsigned)ca.x);
            unsigned s1 = __builtin_amdgcn_readfirstlane((unsigned)ca.y);
            unsigned s2 = __builtin_amdgcn_readfirstlane((unsigned)ca.z);
            unsigned s3 = __builtin_amdgcn_readfirstlane((unsigned)ca.w);
            unsigned v0 = X[((size_t)s0 << 6) + lane];
            unsigned v1 = X[((size_t)s1 << 6) + lane];
            unsigned v2 = X[((size_t)s2 << 6) + lane];
            unsigned v3 = X[((size_t)s3 << 6) + lane];
            ax += blo(v0) + blo(v1) + blo(v2) + blo(v3);
            ay += bhi(v0) + bhi(v1) + bhi(v2) + bhi(v3);
        }
        for (; i < b1; ++i) {
            unsigned s = __builtin_amdgcn_readfirstlane((unsigned)csr[i]);
            unsigned v = X[((size_t)s << 6) + lane];
            ax += blo(v); ay += bhi(v);
        }
    } else {
        const float2* X = (const float2*)Xv;
        for (; i + 3 < b1; i += 4) {
            unsigned s0 = __builtin_amdgcn_readfirstlane((unsigned)csr[i]);
            unsigned s1 = __builtin_amdgcn_readfirstlane((unsigned)csr[i + 1]);
            unsigned s2 = __builtin_amdgcn_readfirstlane((unsigned)csr[i + 2]);
            unsigned s3 = __builtin_amdgcn_readfirstlane((unsigned)csr[i + 3]);
            float2 v0 = X[((size_t)s0 << 6) + lane];
            float2 v1 = X[((size_t)s1 << 6) + lane];
            float2 v2 = X[((size_t)s2 << 6) + lane];
            float2 v3 = X[((size_t)s3 << 6) + lane];
            ax += v0.x + v1.x + v2.x + v3.x;
            ay += v0.y + v1.y + v2.y + v3.y;
        }
        for (; i < b1; ++i) {
            unsigned s = __builtin_amdgcn_readfirstlane((unsigned)csr[i]);
            float2 v = X[((size_t)s << 6) + lane];
            ax += v.x; ay += v.y;
        }
    }
    int dgr = b1 - b0;
    float inv = (dgr > 0) ? 1.0f / (float)dgr : 0.0f;
    unsigned pack = (unsigned)f2b(ax * inv) | ((unsigned)f2b(ay * inv) << 16);
    outb[(long long)wid * 64 + lane] = pack;
}

// ---- MFMA GEMM: Out[r][c] = bias[c] + Am[r]@W[0:128] + Ax[r]@W[128:256] ---
// 512 threads = 8 waves; wave wv owns 16 cols (c0=wv*16), 64 rows (4 frags).
#define WT_SZ   (128 * 264)          // shorts
#define APANEL  (64 * 136)           // shorts
#define ABUF    (2 * APANEL)
#define GEMM_LDS ((WT_SZ + 2 * ABUF) * 2)   // bytes = 137216

template<int XF32, int OUTMODE>
__global__ __launch_bounds__(512, 1) void gemm_mfma_kernel(
    const unsigned short* __restrict__ Am, const void* __restrict__ Ax,
    const float* __restrict__ Wl, const float* __restrict__ Wr,
    const float* __restrict__ bias, void* __restrict__ Out,
    int N, int ntiles)
{
    extern __shared__ unsigned short lds[];
    unsigned short* Wt = lds;
    int t = threadIdx.x;
    int lane = t & 63, wv = t >> 6;
    int lm = lane & 15, q = lane >> 4;
    int c0 = wv * 16;

    // stage Wt[n][k] = (k<128 ? Wl : Wr)[k%128][n], bf16, padded stride 264
    for (int it = 0; it < 32; ++it) {
        int n = t & 127;
        int kp = it * 4 + (t >> 7);           // 0..127
        int k = 2 * kp;
        const float* Wsrc = (k < 128) ? (Wl + k * 128) : (Wr + (k - 128) * 128);
        unsigned pack = (unsigned)f2b(Wsrc[n]) | ((unsigned)f2b(Wsrc[128 + n]) << 16);
        *(unsigned*)(Wt + n * 264 + k) = pack;
    }

    float bias0 = bias[c0 + lm];

    // tile = 64 rows x 16 chunks(short8) per panel = 1024 chunks; 512 thr x j=0..1
    short8 pm[2], px[2];
    auto prefetch = [&](int tl) {
        long long row0 = (long long)tl * 64;
        #pragma unroll
        for (int j = 0; j < 2; ++j) {
            int cid = j * 512 + t;
            int row = cid >> 4, cp = cid & 15;
            long long gr = row0 + row;
            bool ok = gr < (long long)N;
            pm[j] = ok ? *(const short8*)(Am + gr * 128 + cp * 8) : (short8)0;
            if (XF32) {
                short8 s = (short8)0;
                if (ok) {
                    const float* xp = (const float*)Ax + gr * 128 + cp * 8;
                    floatx4 u0 = *(const floatx4*)xp;
                    floatx4 u1 = *(const floatx4*)(xp + 4);
                    s[0] = (short)f2b(u0[0]); s[1] = (short)f2b(u0[1]);
                    s[2] = (short)f2b(u0[2]); s[3] = (short)f2b(u0[3]);
                    s[4] = (short)f2b(u1[0]); s[5] = (short)f2b(u1[1]);
                    s[6] = (short)f2b(u1[2]); s[7] = (short)f2b(u1[3]);
                }
                px[j] = s;
            } else {
                px[j] = ok ? *(const short8*)((const unsigned short*)Ax + gr * 128 + cp * 8)
                           : (short8)0;
            }
        }
    };

    int tile = blockIdx.x;
    if (tile < ntiles) prefetch(tile);
    int buf = 0;
    for (; tile < ntiles; tile += gridDim.x) {
        unsigned short* A = lds + WT_SZ + buf * ABUF;
        __syncthreads();
        #pragma unroll
        for (int j = 0; j < 2; ++j) {
            int cid = j * 512 + t;
            int row = cid >> 4, cp = cid & 15;
            *(short8*)(A + row * 136 + cp * 8) = pm[j];
            *(short8*)(A + APANEL + row * 136 + cp * 8) = px[j];
        }
        __syncthreads();
        int nt = tile + gridDim.x;
        if (nt < ntiles) prefetch(nt);

        floatx4 acc[4];
        #pragma unroll
        for (int rf = 0; rf < 4; ++rf) acc[rf] = (floatx4)bias0;
        #pragma unroll
        for (int ks = 0; ks < 8; ++ks) {
            const unsigned short* P = A + (ks >= 4 ? APANEL : 0);
            int k0 = (ks & 3) * 32 + q * 8;
            short8 b0 = *(const short8*)(Wt + (c0 + lm) * 264 + ks * 32 + q * 8);
            #pragma unroll
            for (int rf = 0; rf < 4; ++rf) {
                short8 a = *(const short8*)(P + (rf * 16 + lm) * 136 + k0);
                acc[rf] = __builtin_amdgcn_mfma_f32_16x16x32_bf16(a, b0, acc[rf], 0, 0, 0);
            }
        }

        long long r0 = (long long)tile * 64;
        int col = c0 + lm;
        #pragma unroll
        for (int rf = 0; rf < 4; ++rf) {
            #pragma unroll
            for (int rg = 0; rg < 4; ++rg) {
                long long rr = r0 + rf * 16 + q * 4 + rg;
                if (rr < (long long)N) {
                    float v = acc[rf][rg];
                    if (OUTMODE != 2) v = fmaxf(v, 0.f);
                    if (OUTMODE == 1)
                        ((unsigned short*)Out)[rr * 128 + col] = f2b(v);
                    else
                        ((float*)Out)[rr * 128 + col] = v;
                }
            }
        }
        buf ^= 1;
    }
}

// ---------------------------------------------------------------------------
extern "C" void kernel_launch(void* const* d_in, const int* in_sizes, int n_in,
                              void* d_out, int out_size, void* d_ws, size_t ws_size,
                              hipStream_t stream) {
    const float* x   = (const float*)d_in[0];
    const int*   eix = (const int*)d_in[1];
    const float* W1l = (const float*)d_in[2];
    const float* b1  = (const float*)d_in[3];
    const float* W1r = (const float*)d_in[4];
    const float* W2l = (const float*)d_in[5];
    const float* b2  = (const float*)d_in[6];
    const float* W2r = (const float*)d_in[7];
    float* out = (float*)d_out;

    int N = in_sizes[0] / 128;
    int E = in_sizes[1] / 2;
    if (N <= 0 || E <= 0) return;
    int nb1 = (N + (1 << BSH1) - 1) >> BSH1;

    char* ws = (char*)d_ws;
    size_t o = 0;
    auto alloc = [&](size_t bytes) -> void* {
        o = (o + 255) & ~(size_t)255;
        void* p = ws + o;
        o += bytes;
        return p;
    };
    int*            flag   = (int*)alloc(4);
    int*            bcnt   = (int*)alloc((size_t)nb1 * 4);
    int*            boff   = (int*)alloc(((size_t)nb1 + 1) * 4);
    int*            bcur   = (int*)alloc((size_t)nb1 * 4);
    int*            off    = (int*)alloc(((size_t)N + 1) * 4);
    int*            csr    = (int*)alloc((size_t)E * 4);
    unsigned short* xb     = (unsigned short*)alloc((size_t)N * 128 * 2);
    unsigned short* meanb  = (unsigned short*)alloc((size_t)N * 128 * 2);
    unsigned short* hb     = (unsigned short*)alloc((size_t)N * 128 * 2);
    bool full = (o <= ws_size);   // room for bf16 h?
    // pairs aliases meanb: dead before spmm writes meanb (needs E*4 <= N*256B)
    unsigned* pairs = (unsigned*)meanb;

    (void)hipFuncSetAttribute((const void*)gemm_mfma_kernel<0, 0>,
                              hipFuncAttributeMaxDynamicSharedMemorySize, GEMM_LDS);
    (void)hipFuncSetAttribute((const void*)gemm_mfma_kernel<0, 1>,
                              hipFuncAttributeMaxDynamicSharedMemorySize, GEMM_LDS);
    (void)hipFuncSetAttribute((const void*)gemm_mfma_kernel<0, 2>,
                              hipFuncAttributeMaxDynamicSharedMemorySize, GEMM_LDS);
    (void)hipFuncSetAttribute((const void*)gemm_mfma_kernel<1, 2>,
                              hipFuncAttributeMaxDynamicSharedMemorySize, GEMM_LDS);

    hipMemsetAsync(bcnt, 0, (size_t)nb1 * 4, stream);

    // CSR build: coarse count -> scan -> chunk-private scatter -> fine sort
    detect_kernel<<<1, 256, 0, stream>>>(eix, in_sizes[1], flag);
    size_t cnt_lds = (size_t)nb1 * 4;
    coarse_count_kernel<<<256, 256, cnt_lds, stream>>>(eix, flag, bcnt, E, nb1);
    scan_kernel<<<1, 1024, 0, stream>>>(bcnt, boff, bcur, nb1);
    int nchunks = (E + CHUNK - 1) / CHUNK;
    int sgrid = nchunks < 2048 ? nchunks : 2048;
    coarse_scatter_kernel<<<sgrid, 256, 2 * cnt_lds, stream>>>(eix, flag, bcur, pairs, E, nb1);
    fine_csr_kernel<<<nb1, 256, 0, stream>>>(pairs, boff, off, csr, N, nb1, E);

    // x -> bf16
    cvt_kernel<<<2048, 256, 0, stream>>>(x, xb, N * 32);

    int spmm_grid = (N + 3) / 4;
    int ntiles = (N + 63) / 64;
    int ggrid = ntiles < 256 ? ntiles : 256;

    // layer 1
    spmm_mean_kernel<1><<<spmm_grid, 256, 0, stream>>>(xb, off, csr, (unsigned*)meanb, N);
    if (full) {
        gemm_mfma_kernel<0, 1><<<ggrid, 512, GEMM_LDS, stream>>>(
            meanb, xb, W1l, W1r, b1, hb, N, ntiles);
        spmm_mean_kernel<1><<<spmm_grid, 256, 0, stream>>>(hb, off, csr, (unsigned*)meanb, N);
        gemm_mfma_kernel<0, 2><<<ggrid, 512, GEMM_LDS, stream>>>(
            meanb, hb, W2l, W2r, b2, out, N, ntiles);
    } else {
        gemm_mfma_kernel<0, 0><<<ggrid, 512, GEMM_LDS, stream>>>(
            meanb, xb, W1l, W1r, b1, out, N, ntiles);
        spmm_mean_kernel<0><<<spmm_grid, 256, 0, stream>>>(out, off, csr, (unsigned*)meanb, N);
        gemm_mfma_kernel<1, 2><<<ggrid, 512, GEMM_LDS, stream>>>(
            meanb, out, W2l, W2r, b2, out, N, ntiles);
    }
}

// Round 8
// 262.109 us; speedup vs baseline: 1.0311x; 1.0311x over previous
//
#include <hip/hip_runtime.h>

// ---------------------------------------------------------------------------
// GraphSAGE 2-layer forward, MI355X (gfx950)
//   h   = relu(mean_agg(x) @ W1l + b1 + x @ W1r)
//   out =      mean_agg(h) @ W2l + b2 + h @ W2r
// R8: revert spmm to R6 form (R7's readfirstlane scalarization regressed:
// gather is memory-floor-bound at ~3.2TB/s, not VALU-bound). Keep reg-cached
// dst in coarse_scatter (single edge-list read, CHUNK=2048 for occupancy).
// ---------------------------------------------------------------------------

typedef __attribute__((ext_vector_type(8))) short short8;
typedef __attribute__((ext_vector_type(4))) float floatx4;
typedef __attribute__((ext_vector_type(4))) unsigned short ushort4v;

#define BSH1 9                     // coarse bucket = 512 consecutive dst nodes
#define CHUNK 2048                 // edges per chunk (coarse scatter)
// packed pair: src in bits[0:23), dst&511 in bits[23:32). requires N < 2^23

__device__ inline unsigned short f2b(float f) {  // f32 -> bf16 (RNE)
    unsigned u = __builtin_bit_cast(unsigned, f);
    return (unsigned short)((u + 0x7FFFu + ((u >> 16) & 1u)) >> 16);
}
__device__ inline float blo(unsigned v) { return __builtin_bit_cast(float, v << 16); }
__device__ inline float bhi(unsigned v) { return __builtin_bit_cast(float, v & 0xffff0000u); }

// ---- edge layout detection (int64 vs int32 buffer) ------------------------
__global__ void detect_kernel(const int* __restrict__ e32, int nelem, int* flag) {
    __shared__ int bad;
    if (threadIdx.x == 0) bad = 0;
    __syncthreads();
    int half = nelem >> 1;  // = E
    int viol = 0;
    for (int i = threadIdx.x; i < 4096; i += blockDim.x) {
        long long k = ((long long)i * half) / 4096;
        if (e32[2 * k + 1] != 0) viol++;   // int64 => hi words all 0
    }
    if (viol) atomicAdd(&bad, viol);
    __syncthreads();
    if (threadIdx.x == 0) flag[0] = (bad == 0) ? 1 : 0;  // 1 = int64 layout
}

__device__ inline void decode_edge(const int* e32, bool is64, int E, int i, int& s, int& d) {
    if (is64) { s = e32[2 * (long long)i]; d = e32[2 * ((long long)E + i)]; }
    else      { s = e32[i];                d = e32[E + i]; }
}

// ---- coarse bucket count: LDS histogram per block, tiny global flush ------
__global__ __launch_bounds__(256) void coarse_count_kernel(const int* __restrict__ e32,
                                                           const int* __restrict__ flag,
                                                           int* __restrict__ bcnt,
                                                           int E, int nb1) {
    extern __shared__ int lh[];
    for (int i = threadIdx.x; i < nb1; i += blockDim.x) lh[i] = 0;
    __syncthreads();
    bool is64 = flag[0] != 0;
    int stride = gridDim.x * blockDim.x;
    for (int i = blockIdx.x * blockDim.x + threadIdx.x; i < E; i += stride) {
        int d = is64 ? e32[2 * ((long long)E + i)] : e32[E + i];
        atomicAdd(&lh[d >> BSH1], 1);
    }
    __syncthreads();
    for (int i = threadIdx.x; i < nb1; i += blockDim.x) {
        int c = lh[i];
        if (c) atomicAdd(&bcnt[i], c);
    }
}

// ---- exclusive scan (single block) ----------------------------------------
__global__ __launch_bounds__(1024) void scan_kernel(const int* __restrict__ deg,
                                                    int* __restrict__ off,
                                                    int* __restrict__ cursor, int N) {
    __shared__ int wsum[16];
    __shared__ int s_carry;
    int t = threadIdx.x;
    int lane = t & 63, w = t >> 6;
    if (t == 0) s_carry = 0;
    __syncthreads();
    for (int base = 0; base < N; base += 1024) {
        int i = base + t;
        int v = (i < N) ? deg[i] : 0;
        int sc = v;
        #pragma unroll
        for (int o = 1; o < 64; o <<= 1) {
            int u = __shfl_up(sc, o, 64);
            if (lane >= o) sc += u;
        }
        if (lane == 63) wsum[w] = sc;
        __syncthreads();
        int woff = 0;
        for (int j = 0; j < w; ++j) woff += wsum[j];
        int c = s_carry;
        int excl = c + woff + (sc - v);
        if (i < N) { off[i] = excl; cursor[i] = excl; }
        __syncthreads();
        if (t == 1023) s_carry = c + woff + sc;
        __syncthreads();
    }
    if (t == 0) off[N] = s_carry;
}

// ---- coarse scatter: dst cached in regs, one reservation per bucket -------
__global__ __launch_bounds__(256) void coarse_scatter_kernel(const int* __restrict__ e32,
                                                             const int* __restrict__ flag,
                                                             int* __restrict__ bcur,
                                                             unsigned* __restrict__ pairs,
                                                             int E, int nb1) {
    extern __shared__ int lh[];            // [nb1] cursor/hist + [nb1] base
    int t = threadIdx.x;
    bool is64 = flag[0] != 0;
    int nchunks = (E + CHUNK - 1) / CHUNK;
    for (int ch = blockIdx.x; ch < nchunks; ch += gridDim.x) {
        int e0 = ch * CHUNK;
        int e1 = min(e0 + CHUNK, E);
        for (int i = t; i < nb1; i += 256) lh[i] = 0;
        __syncthreads();
        int dreg[CHUNK / 256];
        #pragma unroll
        for (int j = 0; j < CHUNK / 256; ++j) {
            int i = e0 + j * 256 + t;
            int d = -1;
            if (i < e1) d = is64 ? e32[2 * ((long long)E + i)] : e32[E + i];
            dreg[j] = d;
            if (d >= 0) atomicAdd(&lh[d >> BSH1], 1);
        }
        __syncthreads();
        for (int i = t; i < nb1; i += 256) {
            int c = lh[i];
            lh[nb1 + i] = c ? atomicAdd(&bcur[i], c) : 0;   // global reservation
            lh[i] = 0;                                      // reuse as local cursor
        }
        __syncthreads();
        #pragma unroll
        for (int j = 0; j < CHUNK / 256; ++j) {
            int i = e0 + j * 256 + t;
            if (i < e1) {
                int s = is64 ? e32[2 * (long long)i] : e32[i];
                int d = dreg[j];
                int k = d >> BSH1;
                int r = atomicAdd(&lh[k], 1);
                pairs[lh[nb1 + k] + r] = (unsigned)s | ((unsigned)(d & ((1 << BSH1) - 1)) << 23);
            }
        }
        __syncthreads();
    }
}

// ---- fine CSR build: one block per coarse bucket (region L2-resident) -----
__global__ __launch_bounds__(256) void fine_csr_kernel(const unsigned* __restrict__ pairs,
                                                       const int* __restrict__ boff,
                                                       int* __restrict__ off,
                                                       int* __restrict__ csr,
                                                       int N, int nb1, int E) {
    __shared__ int ldeg[512], loff[512];
    __shared__ int wsum[4];
    int b = blockIdx.x;
    if (b >= nb1) return;
    int t = threadIdx.x;
    int p0 = boff[b], p1 = boff[b + 1];
    int base = b << BSH1;
    ldeg[2 * t] = 0; ldeg[2 * t + 1] = 0;
    __syncthreads();
    for (int i = p0 + t; i < p1; i += 256) atomicAdd(&ldeg[pairs[i] >> 23], 1);
    __syncthreads();
    // exclusive scan of 512 entries with 256 threads
    {
        int lane = t & 63, w = t >> 6;
        int v0 = ldeg[2 * t], v1 = ldeg[2 * t + 1];
        int v = v0 + v1, sc = v;
        #pragma unroll
        for (int o = 1; o < 64; o <<= 1) {
            int u = __shfl_up(sc, o, 64);
            if (lane >= o) sc += u;
        }
        if (lane == 63) wsum[w] = sc;
        __syncthreads();
        int cross = 0;
        for (int j = 0; j < w; ++j) cross += wsum[j];
        int ex = cross + sc - v;
        loff[2 * t] = ex;
        loff[2 * t + 1] = ex + v0;
        int d0 = base + 2 * t, d1 = d0 + 1;
        if (d0 < N) off[d0] = p0 + ex;
        if (d1 < N) off[d1] = p0 + ex + v0;
    }
    __syncthreads();
    ldeg[2 * t] = 0; ldeg[2 * t + 1] = 0;   // reuse as cursors
    __syncthreads();
    for (int i = p0 + t; i < p1; i += 256) {
        unsigned e = pairs[i];
        int dl = e >> 23;
        int r = atomicAdd(&ldeg[dl], 1);
        csr[p0 + loff[dl] + r] = (int)(e & 0x7FFFFFu);
    }
    if (b == 0 && t == 0) off[N] = E;
}

// ---- f32 -> bf16 table ----------------------------------------------------
__global__ void cvt_kernel(const float* __restrict__ in, unsigned short* __restrict__ out, int n4) {
    int stride = gridDim.x * blockDim.x;
    for (int i = blockIdx.x * blockDim.x + threadIdx.x; i < n4; i += stride) {
        float4 v = ((const float4*)in)[i];
        ushort4v o;
        o[0] = f2b(v.x); o[1] = f2b(v.y); o[2] = f2b(v.z); o[3] = f2b(v.w);
        ((ushort4v*)out)[i] = o;
    }
}

// ---- SpMM mean: gather rows of X (bf16 or f32), write bf16 mean -----------
// one wave per node; unroll 8 for memory-level parallelism (R6 winner form)
template<int BF16IN>
__global__ __launch_bounds__(256) void spmm_mean_kernel(const void* __restrict__ Xv,
                                                        const int* __restrict__ off,
                                                        const int* __restrict__ csr,
                                                        unsigned* __restrict__ outb, int N) {
    int wid = blockIdx.x * 4 + (threadIdx.x >> 6);
    int lane = threadIdx.x & 63;
    if (wid >= N) return;
    int b0 = off[wid], b1 = off[wid + 1];
    float ax = 0.f, ay = 0.f;
    int i = b0;
    if (BF16IN) {
        const unsigned* X = (const unsigned*)Xv;   // row = 64 uints (128 bf16)
        for (; i + 7 < b1; i += 8) {
            int s0 = csr[i],     s1 = csr[i + 1], s2 = csr[i + 2], s3 = csr[i + 3];
            int s4 = csr[i + 4], s5 = csr[i + 5], s6 = csr[i + 6], s7 = csr[i + 7];
            unsigned v0 = X[(long long)s0 * 64 + lane];
            unsigned v1 = X[(long long)s1 * 64 + lane];
            unsigned v2 = X[(long long)s2 * 64 + lane];
            unsigned v3 = X[(long long)s3 * 64 + lane];
            unsigned v4 = X[(long long)s4 * 64 + lane];
            unsigned v5 = X[(long long)s5 * 64 + lane];
            unsigned v6 = X[(long long)s6 * 64 + lane];
            unsigned v7 = X[(long long)s7 * 64 + lane];
            ax += (blo(v0) + blo(v1)) + (blo(v2) + blo(v3)) +
                  ((blo(v4) + blo(v5)) + (blo(v6) + blo(v7)));
            ay += (bhi(v0) + bhi(v1)) + (bhi(v2) + bhi(v3)) +
                  ((bhi(v4) + bhi(v5)) + (bhi(v6) + bhi(v7)));
        }
        for (; i + 3 < b1; i += 4) {
            int s0 = csr[i], s1 = csr[i + 1], s2 = csr[i + 2], s3 = csr[i + 3];
            unsigned v0 = X[(long long)s0 * 64 + lane];
            unsigned v1 = X[(long long)s1 * 64 + lane];
            unsigned v2 = X[(long long)s2 * 64 + lane];
            unsigned v3 = X[(long long)s3 * 64 + lane];
            ax += blo(v0) + blo(v1) + blo(v2) + blo(v3);
            ay += bhi(v0) + bhi(v1) + bhi(v2) + bhi(v3);
        }
        for (; i < b1; ++i) {
            unsigned v = X[(long long)csr[i] * 64 + lane];
            ax += blo(v); ay += bhi(v);
        }
    } else {
        const float2* X = (const float2*)Xv;
        for (; i + 3 < b1; i += 4) {
            int s0 = csr[i], s1 = csr[i + 1], s2 = csr[i + 2], s3 = csr[i + 3];
            float2 v0 = X[(long long)s0 * 64 + lane];
            float2 v1 = X[(long long)s1 * 64 + lane];
            float2 v2 = X[(long long)s2 * 64 + lane];
            float2 v3 = X[(long long)s3 * 64 + lane];
            ax += v0.x + v1.x + v2.x + v3.x;
            ay += v0.y + v1.y + v2.y + v3.y;
        }
        for (; i < b1; ++i) {
            float2 v = X[(long long)csr[i] * 64 + lane];
            ax += v.x; ay += v.y;
        }
    }
    int dgr = b1 - b0;
    float inv = (dgr > 0) ? 1.0f / (float)dgr : 0.0f;
    unsigned pack = (unsigned)f2b(ax * inv) | ((unsigned)f2b(ay * inv) << 16);
    outb[(long long)wid * 64 + lane] = pack;
}

// ---- MFMA GEMM: Out[r][c] = bias[c] + Am[r]@W[0:128] + Ax[r]@W[128:256] ---
// 512 threads = 8 waves; wave wv owns 16 cols (c0=wv*16), 64 rows (4 frags).
#define WT_SZ   (128 * 264)          // shorts
#define APANEL  (64 * 136)           // shorts
#define ABUF    (2 * APANEL)
#define GEMM_LDS ((WT_SZ + 2 * ABUF) * 2)   // bytes = 137216

template<int XF32, int OUTMODE>
__global__ __launch_bounds__(512, 1) void gemm_mfma_kernel(
    const unsigned short* __restrict__ Am, const void* __restrict__ Ax,
    const float* __restrict__ Wl, const float* __restrict__ Wr,
    const float* __restrict__ bias, void* __restrict__ Out,
    int N, int ntiles)
{
    extern __shared__ unsigned short lds[];
    unsigned short* Wt = lds;
    int t = threadIdx.x;
    int lane = t & 63, wv = t >> 6;
    int lm = lane & 15, q = lane >> 4;
    int c0 = wv * 16;

    // stage Wt[n][k] = (k<128 ? Wl : Wr)[k%128][n], bf16, padded stride 264
    for (int it = 0; it < 32; ++it) {
        int n = t & 127;
        int kp = it * 4 + (t >> 7);           // 0..127
        int k = 2 * kp;
        const float* Wsrc = (k < 128) ? (Wl + k * 128) : (Wr + (k - 128) * 128);
        unsigned pack = (unsigned)f2b(Wsrc[n]) | ((unsigned)f2b(Wsrc[128 + n]) << 16);
        *(unsigned*)(Wt + n * 264 + k) = pack;
    }

    float bias0 = bias[c0 + lm];

    // tile = 64 rows x 16 chunks(short8) per panel = 1024 chunks; 512 thr x j=0..1
    short8 pm[2], px[2];
    auto prefetch = [&](int tl) {
        long long row0 = (long long)tl * 64;
        #pragma unroll
        for (int j = 0; j < 2; ++j) {
            int cid = j * 512 + t;
            int row = cid >> 4, cp = cid & 15;
            long long gr = row0 + row;
            bool ok = gr < (long long)N;
            pm[j] = ok ? *(const short8*)(Am + gr * 128 + cp * 8) : (short8)0;
            if (XF32) {
                short8 s = (short8)0;
                if (ok) {
                    const float* xp = (const float*)Ax + gr * 128 + cp * 8;
                    floatx4 u0 = *(const floatx4*)xp;
                    floatx4 u1 = *(const floatx4*)(xp + 4);
                    s[0] = (short)f2b(u0[0]); s[1] = (short)f2b(u0[1]);
                    s[2] = (short)f2b(u0[2]); s[3] = (short)f2b(u0[3]);
                    s[4] = (short)f2b(u1[0]); s[5] = (short)f2b(u1[1]);
                    s[6] = (short)f2b(u1[2]); s[7] = (short)f2b(u1[3]);
                }
                px[j] = s;
            } else {
                px[j] = ok ? *(const short8*)((const unsigned short*)Ax + gr * 128 + cp * 8)
                           : (short8)0;
            }
        }
    };

    int tile = blockIdx.x;
    if (tile < ntiles) prefetch(tile);
    int buf = 0;
    for (; tile < ntiles; tile += gridDim.x) {
        unsigned short* A = lds + WT_SZ + buf * ABUF;
        __syncthreads();
        #pragma unroll
        for (int j = 0; j < 2; ++j) {
            int cid = j * 512 + t;
            int row = cid >> 4, cp = cid & 15;
            *(short8*)(A + row * 136 + cp * 8) = pm[j];
            *(short8*)(A + APANEL + row * 136 + cp * 8) = px[j];
        }
        __syncthreads();
        int nt = tile + gridDim.x;
        if (nt < ntiles) prefetch(nt);

        floatx4 acc[4];
        #pragma unroll
        for (int rf = 0; rf < 4; ++rf) acc[rf] = (floatx4)bias0;
        #pragma unroll
        for (int ks = 0; ks < 8; ++ks) {
            const unsigned short* P = A + (ks >= 4 ? APANEL : 0);
            int k0 = (ks & 3) * 32 + q * 8;
            short8 b0 = *(const short8*)(Wt + (c0 + lm) * 264 + ks * 32 + q * 8);
            #pragma unroll
            for (int rf = 0; rf < 4; ++rf) {
                short8 a = *(const short8*)(P + (rf * 16 + lm) * 136 + k0);
                acc[rf] = __builtin_amdgcn_mfma_f32_16x16x32_bf16(a, b0, acc[rf], 0, 0, 0);
            }
        }

        long long r0 = (long long)tile * 64;
        int col = c0 + lm;
        #pragma unroll
        for (int rf = 0; rf < 4; ++rf) {
            #pragma unroll
            for (int rg = 0; rg < 4; ++rg) {
                long long rr = r0 + rf * 16 + q * 4 + rg;
                if (rr < (long long)N) {
                    float v = acc[rf][rg];
                    if (OUTMODE != 2) v = fmaxf(v, 0.f);
                    if (OUTMODE == 1)
                        ((unsigned short*)Out)[rr * 128 + col] = f2b(v);
                    else
                        ((float*)Out)[rr * 128 + col] = v;
                }
            }
        }
        buf ^= 1;
    }
}

// ---------------------------------------------------------------------------
extern "C" void kernel_launch(void* const* d_in, const int* in_sizes, int n_in,
                              void* d_out, int out_size, void* d_ws, size_t ws_size,
                              hipStream_t stream) {
    const float* x   = (const float*)d_in[0];
    const int*   eix = (const int*)d_in[1];
    const float* W1l = (const float*)d_in[2];
    const float* b1  = (const float*)d_in[3];
    const float* W1r = (const float*)d_in[4];
    const float* W2l = (const float*)d_in[5];
    const float* b2  = (const float*)d_in[6];
    const float* W2r = (const float*)d_in[7];
    float* out = (float*)d_out;

    int N = in_sizes[0] / 128;
    int E = in_sizes[1] / 2;
    if (N <= 0 || E <= 0) return;
    int nb1 = (N + (1 << BSH1) - 1) >> BSH1;

    char* ws = (char*)d_ws;
    size_t o = 0;
    auto alloc = [&](size_t bytes) -> void* {
        o = (o + 255) & ~(size_t)255;
        void* p = ws + o;
        o += bytes;
        return p;
    };
    int*            flag   = (int*)alloc(4);
    int*            bcnt   = (int*)alloc((size_t)nb1 * 4);
    int*            boff   = (int*)alloc(((size_t)nb1 + 1) * 4);
    int*            bcur   = (int*)alloc((size_t)nb1 * 4);
    int*            off    = (int*)alloc(((size_t)N + 1) * 4);
    int*            csr    = (int*)alloc((size_t)E * 4);
    unsigned short* xb     = (unsigned short*)alloc((size_t)N * 128 * 2);
    unsigned short* meanb  = (unsigned short*)alloc((size_t)N * 128 * 2);
    unsigned short* hb     = (unsigned short*)alloc((size_t)N * 128 * 2);
    bool full = (o <= ws_size);   // room for bf16 h?
    // pairs aliases meanb: dead before spmm writes meanb (needs E*4 <= N*256B)
    unsigned* pairs = (unsigned*)meanb;

    (void)hipFuncSetAttribute((const void*)gemm_mfma_kernel<0, 0>,
                              hipFuncAttributeMaxDynamicSharedMemorySize, GEMM_LDS);
    (void)hipFuncSetAttribute((const void*)gemm_mfma_kernel<0, 1>,
                              hipFuncAttributeMaxDynamicSharedMemorySize, GEMM_LDS);
    (void)hipFuncSetAttribute((const void*)gemm_mfma_kernel<0, 2>,
                              hipFuncAttributeMaxDynamicSharedMemorySize, GEMM_LDS);
    (void)hipFuncSetAttribute((const void*)gemm_mfma_kernel<1, 2>,
                              hipFuncAttributeMaxDynamicSharedMemorySize, GEMM_LDS);

    hipMemsetAsync(bcnt, 0, (size_t)nb1 * 4, stream);

    // CSR build: coarse count -> scan -> chunk-private scatter -> fine sort
    detect_kernel<<<1, 256, 0, stream>>>(eix, in_sizes[1], flag);
    size_t cnt_lds = (size_t)nb1 * 4;
    coarse_count_kernel<<<256, 256, cnt_lds, stream>>>(eix, flag, bcnt, E, nb1);
    scan_kernel<<<1, 1024, 0, stream>>>(bcnt, boff, bcur, nb1);
    int nchunks = (E + CHUNK - 1) / CHUNK;
    int sgrid = nchunks < 2048 ? nchunks : 2048;
    coarse_scatter_kernel<<<sgrid, 256, 2 * cnt_lds, stream>>>(eix, flag, bcur, pairs, E, nb1);
    fine_csr_kernel<<<nb1, 256, 0, stream>>>(pairs, boff, off, csr, N, nb1, E);

    // x -> bf16
    cvt_kernel<<<2048, 256, 0, stream>>>(x, xb, N * 32);

    int spmm_grid = (N + 3) / 4;
    int ntiles = (N + 63) / 64;
    int ggrid = ntiles < 256 ? ntiles : 256;

    // layer 1
    spmm_mean_kernel<1><<<spmm_grid, 256, 0, stream>>>(xb, off, csr, (unsigned*)meanb, N);
    if (full) {
        gemm_mfma_kernel<0, 1><<<ggrid, 512, GEMM_LDS, stream>>>(
            meanb, xb, W1l, W1r, b1, hb, N, ntiles);
        spmm_mean_kernel<1><<<spmm_grid, 256, 0, stream>>>(hb, off, csr, (unsigned*)meanb, N);
        gemm_mfma_kernel<0, 2><<<ggrid, 512, GEMM_LDS, stream>>>(
            meanb, hb, W2l, W2r, b2, out, N, ntiles);
    } else {
        gemm_mfma_kernel<0, 0><<<ggrid, 512, GEMM_LDS, stream>>>(
            meanb, xb, W1l, W1r, b1, out, N, ntiles);
        spmm_mean_kernel<0><<<spmm_grid, 256, 0, stream>>>(out, off, csr, (unsigned*)meanb, N);
        gemm_mfma_kernel<1, 2><<<ggrid, 512, GEMM_LDS, stream>>>(
            meanb, out, W2l, W2r, b2, out, N, ntiles);
    }
}

// Round 9
// 255.706 us; speedup vs baseline: 1.0569x; 1.0250x over previous
//
#include <hip/hip_runtime.h>

// ---------------------------------------------------------------------------
// GraphSAGE 2-layer forward, MI355X (gfx950)
//   h   = relu(mean_agg(x) @ W1l + b1 + x @ W1r)
//   out =      mean_agg(h) @ W2l + b2 + h @ W2r
// R9: GEMM v2 - W held in registers (B-frags), LDS overlay: Wt staging then
// A double-buffer in the SAME 69.6KB -> 2 blocks/CU (was 137KB, 1 block/CU).
// Fused cvt+coarse_count kernel. spmm/CSR pipeline unchanged from R8.
// ---------------------------------------------------------------------------

typedef __attribute__((ext_vector_type(8))) short short8;
typedef __attribute__((ext_vector_type(4))) float floatx4;
typedef __attribute__((ext_vector_type(4))) unsigned short ushort4v;

#define BSH1 9                     // coarse bucket = 512 consecutive dst nodes
#define CHUNK 2048                 // edges per chunk (coarse scatter)
// packed pair: src in bits[0:23), dst&511 in bits[23:32). requires N < 2^23

__device__ inline unsigned short f2b(float f) {  // f32 -> bf16 (RNE)
    unsigned u = __builtin_bit_cast(unsigned, f);
    return (unsigned short)((u + 0x7FFFu + ((u >> 16) & 1u)) >> 16);
}
__device__ inline float blo(unsigned v) { return __builtin_bit_cast(float, v << 16); }
__device__ inline float bhi(unsigned v) { return __builtin_bit_cast(float, v & 0xffff0000u); }

// ---- edge layout detection (int64 vs int32 buffer) ------------------------
__global__ void detect_kernel(const int* __restrict__ e32, int nelem, int* flag) {
    __shared__ int bad;
    if (threadIdx.x == 0) bad = 0;
    __syncthreads();
    int half = nelem >> 1;  // = E
    int viol = 0;
    for (int i = threadIdx.x; i < 4096; i += blockDim.x) {
        long long k = ((long long)i * half) / 4096;
        if (e32[2 * k + 1] != 0) viol++;   // int64 => hi words all 0
    }
    if (viol) atomicAdd(&bad, viol);
    __syncthreads();
    if (threadIdx.x == 0) flag[0] = (bad == 0) ? 1 : 0;  // 1 = int64 layout
}

__device__ inline void decode_edge(const int* e32, bool is64, int E, int i, int& s, int& d) {
    if (is64) { s = e32[2 * (long long)i]; d = e32[2 * ((long long)E + i)]; }
    else      { s = e32[i];                d = e32[E + i]; }
}

// ---- fused: x->bf16 convert (blocks [0,cvtB)) + coarse count (rest) -------
__global__ __launch_bounds__(256) void cvt_count_kernel(const float* __restrict__ xin,
                                                        unsigned short* __restrict__ xb, int n4,
                                                        const int* __restrict__ e32,
                                                        const int* __restrict__ flag,
                                                        int* __restrict__ bcnt,
                                                        int E, int nb1, int cvtB) {
    if ((int)blockIdx.x < cvtB) {
        int stride = cvtB * 256;
        for (int i = blockIdx.x * 256 + threadIdx.x; i < n4; i += stride) {
            float4 v = ((const float4*)xin)[i];
            ushort4v o;
            o[0] = f2b(v.x); o[1] = f2b(v.y); o[2] = f2b(v.z); o[3] = f2b(v.w);
            ((ushort4v*)xb)[i] = o;
        }
    } else {
        extern __shared__ int lh[];
        for (int i = threadIdx.x; i < nb1; i += 256) lh[i] = 0;
        __syncthreads();
        bool is64 = flag[0] != 0;
        int cb = gridDim.x - cvtB;
        int stride = cb * 256;
        for (int i = (blockIdx.x - cvtB) * 256 + threadIdx.x; i < E; i += stride) {
            int d = is64 ? e32[2 * ((long long)E + i)] : e32[E + i];
            atomicAdd(&lh[d >> BSH1], 1);
        }
        __syncthreads();
        for (int i = threadIdx.x; i < nb1; i += 256) {
            int c = lh[i];
            if (c) atomicAdd(&bcnt[i], c);
        }
    }
}

// ---- exclusive scan (single block) ----------------------------------------
__global__ __launch_bounds__(1024) void scan_kernel(const int* __restrict__ deg,
                                                    int* __restrict__ off,
                                                    int* __restrict__ cursor, int N) {
    __shared__ int wsum[16];
    __shared__ int s_carry;
    int t = threadIdx.x;
    int lane = t & 63, w = t >> 6;
    if (t == 0) s_carry = 0;
    __syncthreads();
    for (int base = 0; base < N; base += 1024) {
        int i = base + t;
        int v = (i < N) ? deg[i] : 0;
        int sc = v;
        #pragma unroll
        for (int o = 1; o < 64; o <<= 1) {
            int u = __shfl_up(sc, o, 64);
            if (lane >= o) sc += u;
        }
        if (lane == 63) wsum[w] = sc;
        __syncthreads();
        int woff = 0;
        for (int j = 0; j < w; ++j) woff += wsum[j];
        int c = s_carry;
        int excl = c + woff + (sc - v);
        if (i < N) { off[i] = excl; cursor[i] = excl; }
        __syncthreads();
        if (t == 1023) s_carry = c + woff + sc;
        __syncthreads();
    }
    if (t == 0) off[N] = s_carry;
}

// ---- coarse scatter: dst cached in regs, one reservation per bucket -------
__global__ __launch_bounds__(256) void coarse_scatter_kernel(const int* __restrict__ e32,
                                                             const int* __restrict__ flag,
                                                             int* __restrict__ bcur,
                                                             unsigned* __restrict__ pairs,
                                                             int E, int nb1) {
    extern __shared__ int lh[];            // [nb1] cursor/hist + [nb1] base
    int t = threadIdx.x;
    bool is64 = flag[0] != 0;
    int nchunks = (E + CHUNK - 1) / CHUNK;
    for (int ch = blockIdx.x; ch < nchunks; ch += gridDim.x) {
        int e0 = ch * CHUNK;
        int e1 = min(e0 + CHUNK, E);
        for (int i = t; i < nb1; i += 256) lh[i] = 0;
        __syncthreads();
        int dreg[CHUNK / 256];
        #pragma unroll
        for (int j = 0; j < CHUNK / 256; ++j) {
            int i = e0 + j * 256 + t;
            int d = -1;
            if (i < e1) d = is64 ? e32[2 * ((long long)E + i)] : e32[E + i];
            dreg[j] = d;
            if (d >= 0) atomicAdd(&lh[d >> BSH1], 1);
        }
        __syncthreads();
        for (int i = t; i < nb1; i += 256) {
            int c = lh[i];
            lh[nb1 + i] = c ? atomicAdd(&bcur[i], c) : 0;   // global reservation
            lh[i] = 0;                                      // reuse as local cursor
        }
        __syncthreads();
        #pragma unroll
        for (int j = 0; j < CHUNK / 256; ++j) {
            int i = e0 + j * 256 + t;
            if (i < e1) {
                int s = is64 ? e32[2 * (long long)i] : e32[i];
                int d = dreg[j];
                int k = d >> BSH1;
                int r = atomicAdd(&lh[k], 1);
                pairs[lh[nb1 + k] + r] = (unsigned)s | ((unsigned)(d & ((1 << BSH1) - 1)) << 23);
            }
        }
        __syncthreads();
    }
}

// ---- fine CSR build: one block per coarse bucket (region L2-resident) -----
__global__ __launch_bounds__(256) void fine_csr_kernel(const unsigned* __restrict__ pairs,
                                                       const int* __restrict__ boff,
                                                       int* __restrict__ off,
                                                       int* __restrict__ csr,
                                                       int N, int nb1, int E) {
    __shared__ int ldeg[512], loff[512];
    __shared__ int wsum[4];
    int b = blockIdx.x;
    if (b >= nb1) return;
    int t = threadIdx.x;
    int p0 = boff[b], p1 = boff[b + 1];
    int base = b << BSH1;
    ldeg[2 * t] = 0; ldeg[2 * t + 1] = 0;
    __syncthreads();
    for (int i = p0 + t; i < p1; i += 256) atomicAdd(&ldeg[pairs[i] >> 23], 1);
    __syncthreads();
    // exclusive scan of 512 entries with 256 threads
    {
        int lane = t & 63, w = t >> 6;
        int v0 = ldeg[2 * t], v1 = ldeg[2 * t + 1];
        int v = v0 + v1, sc = v;
        #pragma unroll
        for (int o = 1; o < 64; o <<= 1) {
            int u = __shfl_up(sc, o, 64);
            if (lane >= o) sc += u;
        }
        if (lane == 63) wsum[w] = sc;
        __syncthreads();
        int cross = 0;
        for (int j = 0; j < w; ++j) cross += wsum[j];
        int ex = cross + sc - v;
        loff[2 * t] = ex;
        loff[2 * t + 1] = ex + v0;
        int d0 = base + 2 * t, d1 = d0 + 1;
        if (d0 < N) off[d0] = p0 + ex;
        if (d1 < N) off[d1] = p0 + ex + v0;
    }
    __syncthreads();
    ldeg[2 * t] = 0; ldeg[2 * t + 1] = 0;   // reuse as cursors
    __syncthreads();
    for (int i = p0 + t; i < p1; i += 256) {
        unsigned e = pairs[i];
        int dl = e >> 23;
        int r = atomicAdd(&ldeg[dl], 1);
        csr[p0 + loff[dl] + r] = (int)(e & 0x7FFFFFu);
    }
    if (b == 0 && t == 0) off[N] = E;
}

// ---- SpMM mean: gather rows of X (bf16 or f32), write bf16 mean -----------
// one wave per node; unroll 8 for memory-level parallelism (R6 winner form)
template<int BF16IN>
__global__ __launch_bounds__(256) void spmm_mean_kernel(const void* __restrict__ Xv,
                                                        const int* __restrict__ off,
                                                        const int* __restrict__ csr,
                                                        unsigned* __restrict__ outb, int N) {
    int wid = blockIdx.x * 4 + (threadIdx.x >> 6);
    int lane = threadIdx.x & 63;
    if (wid >= N) return;
    int b0 = off[wid], b1 = off[wid + 1];
    float ax = 0.f, ay = 0.f;
    int i = b0;
    if (BF16IN) {
        const unsigned* X = (const unsigned*)Xv;   // row = 64 uints (128 bf16)
        for (; i + 7 < b1; i += 8) {
            int s0 = csr[i],     s1 = csr[i + 1], s2 = csr[i + 2], s3 = csr[i + 3];
            int s4 = csr[i + 4], s5 = csr[i + 5], s6 = csr[i + 6], s7 = csr[i + 7];
            unsigned v0 = X[(long long)s0 * 64 + lane];
            unsigned v1 = X[(long long)s1 * 64 + lane];
            unsigned v2 = X[(long long)s2 * 64 + lane];
            unsigned v3 = X[(long long)s3 * 64 + lane];
            unsigned v4 = X[(long long)s4 * 64 + lane];
            unsigned v5 = X[(long long)s5 * 64 + lane];
            unsigned v6 = X[(long long)s6 * 64 + lane];
            unsigned v7 = X[(long long)s7 * 64 + lane];
            ax += (blo(v0) + blo(v1)) + (blo(v2) + blo(v3)) +
                  ((blo(v4) + blo(v5)) + (blo(v6) + blo(v7)));
            ay += (bhi(v0) + bhi(v1)) + (bhi(v2) + bhi(v3)) +
                  ((bhi(v4) + bhi(v5)) + (bhi(v6) + bhi(v7)));
        }
        for (; i + 3 < b1; i += 4) {
            int s0 = csr[i], s1 = csr[i + 1], s2 = csr[i + 2], s3 = csr[i + 3];
            unsigned v0 = X[(long long)s0 * 64 + lane];
            unsigned v1 = X[(long long)s1 * 64 + lane];
            unsigned v2 = X[(long long)s2 * 64 + lane];
            unsigned v3 = X[(long long)s3 * 64 + lane];
            ax += blo(v0) + blo(v1) + blo(v2) + blo(v3);
            ay += bhi(v0) + bhi(v1) + bhi(v2) + bhi(v3);
        }
        for (; i < b1; ++i) {
            unsigned v = X[(long long)csr[i] * 64 + lane];
            ax += blo(v); ay += bhi(v);
        }
    } else {
        const float2* X = (const float2*)Xv;
        for (; i + 3 < b1; i += 4) {
            int s0 = csr[i], s1 = csr[i + 1], s2 = csr[i + 2], s3 = csr[i + 3];
            float2 v0 = X[(long long)s0 * 64 + lane];
            float2 v1 = X[(long long)s1 * 64 + lane];
            float2 v2 = X[(long long)s2 * 64 + lane];
            float2 v3 = X[(long long)s3 * 64 + lane];
            ax += v0.x + v1.x + v2.x + v3.x;
            ay += v0.y + v1.y + v2.y + v3.y;
        }
        for (; i < b1; ++i) {
            float2 v = X[(long long)csr[i] * 64 + lane];
            ax += v.x; ay += v.y;
        }
    }
    int dgr = b1 - b0;
    float inv = (dgr > 0) ? 1.0f / (float)dgr : 0.0f;
    unsigned pack = (unsigned)f2b(ax * inv) | ((unsigned)f2b(ay * inv) << 16);
    outb[(long long)wid * 64 + lane] = pack;
}

// ---- MFMA GEMM v2: Out[r][c] = bias[c] + Am[r]@W[0:128] + Ax[r]@W[128:256]
// 512 thr / 8 waves; wave wv owns 16 cols. W staged via LDS ONCE -> B-frags
// in registers (breg[8], 32 VGPR); then the SAME LDS is reused as the A
// double-buffer. LDS = 69.6KB -> 2 blocks/CU.
#define APAD       136                       // A panel row stride (shorts)
#define WT_STRIDE  264
#define WT_SHORTS  (128 * WT_STRIDE)         // 33792 shorts
#define APANEL2    (64 * APAD)               // 8704 shorts
#define ABUF2      (2 * APANEL2)             // Am+Ax panels = 17408 shorts
#define GEMM_LDS   (2 * ABUF2 * 2)           // dbuf bytes = 69632 (> WT bytes 67584)

template<int XF32, int OUTMODE>
__global__ __launch_bounds__(512, 4) void gemm_mfma_kernel(
    const unsigned short* __restrict__ Am, const void* __restrict__ Ax,
    const float* __restrict__ Wl, const float* __restrict__ Wr,
    const float* __restrict__ bias, void* __restrict__ Out,
    int N, int ntiles)
{
    extern __shared__ unsigned short lds[];
    int t = threadIdx.x;
    int lane = t & 63, wv = t >> 6;
    int lm = lane & 15, q = lane >> 4;
    int c0 = wv * 16;

    // phase 0: stage Wt[n][k] = (k<128?Wl:Wr)[k%128][n] into LDS, pull B-frags
    for (int it = 0; it < 32; ++it) {
        int n = t & 127;
        int kp = it * 4 + (t >> 7);           // 0..127
        int k = 2 * kp;
        const float* Wsrc = (k < 128) ? (Wl + k * 128) : (Wr + (k - 128) * 128);
        unsigned pack = (unsigned)f2b(Wsrc[n]) | ((unsigned)f2b(Wsrc[128 + n]) << 16);
        *(unsigned*)(lds + n * WT_STRIDE + k) = pack;
    }
    __syncthreads();
    short8 breg[8];
    #pragma unroll
    for (int ks = 0; ks < 8; ++ks)
        breg[ks] = *(const short8*)(lds + (c0 + lm) * WT_STRIDE + ks * 32 + q * 8);
    __syncthreads();   // all B-frag reads done before LDS is reused for A

    float bias0 = bias[c0 + lm];

    // tile = 64 rows x 16 chunks(short8) per panel = 1024 chunks; 512 thr x j=0..1
    short8 pm[2], px[2];
    auto prefetch = [&](int tl) {
        long long row0 = (long long)tl * 64;
        #pragma unroll
        for (int j = 0; j < 2; ++j) {
            int cid = j * 512 + t;
            int row = cid >> 4, cp = cid & 15;
            long long gr = row0 + row;
            bool ok = gr < (long long)N;
            pm[j] = ok ? *(const short8*)(Am + gr * 128 + cp * 8) : (short8)0;
            if (XF32) {
                short8 s = (short8)0;
                if (ok) {
                    const float* xp = (const float*)Ax + gr * 128 + cp * 8;
                    floatx4 u0 = *(const floatx4*)xp;
                    floatx4 u1 = *(const floatx4*)(xp + 4);
                    s[0] = (short)f2b(u0[0]); s[1] = (short)f2b(u0[1]);
                    s[2] = (short)f2b(u0[2]); s[3] = (short)f2b(u0[3]);
                    s[4] = (short)f2b(u1[0]); s[5] = (short)f2b(u1[1]);
                    s[6] = (short)f2b(u1[2]); s[7] = (short)f2b(u1[3]);
                }
                px[j] = s;
            } else {
                px[j] = ok ? *(const short8*)((const unsigned short*)Ax + gr * 128 + cp * 8)
                           : (short8)0;
            }
        }
    };

    int tile = blockIdx.x;
    if (tile < ntiles) prefetch(tile);
    int buf = 0;
    for (; tile < ntiles; tile += gridDim.x) {
        unsigned short* A = lds + buf * ABUF2;
        __syncthreads();   // prior reads of this buffer done (and phase-0 done)
        #pragma unroll
        for (int j = 0; j < 2; ++j) {
            int cid = j * 512 + t;
            int row = cid >> 4, cp = cid & 15;
            *(short8*)(A + row * APAD + cp * 8) = pm[j];
            *(short8*)(A + APANEL2 + row * APAD + cp * 8) = px[j];
        }
        __syncthreads();   // tile staged
        int nt = tile + gridDim.x;
        if (nt < ntiles) prefetch(nt);

        floatx4 acc[4];
        #pragma unroll
        for (int rf = 0; rf < 4; ++rf) acc[rf] = (floatx4)bias0;
        #pragma unroll
        for (int ks = 0; ks < 8; ++ks) {
            const unsigned short* P = A + (ks >= 4 ? APANEL2 : 0);
            int k0 = (ks & 3) * 32 + q * 8;
            #pragma unroll
            for (int rf = 0; rf < 4; ++rf) {
                short8 a = *(const short8*)(P + (rf * 16 + lm) * APAD + k0);
                acc[rf] = __builtin_amdgcn_mfma_f32_16x16x32_bf16(a, breg[ks], acc[rf], 0, 0, 0);
            }
        }

        long long r0 = (long long)tile * 64;
        int col = c0 + lm;
        #pragma unroll
        for (int rf = 0; rf < 4; ++rf) {
            #pragma unroll
            for (int rg = 0; rg < 4; ++rg) {
                long long rr = r0 + rf * 16 + q * 4 + rg;
                if (rr < (long long)N) {
                    float v = acc[rf][rg];
                    if (OUTMODE != 2) v = fmaxf(v, 0.f);
                    if (OUTMODE == 1)
                        ((unsigned short*)Out)[rr * 128 + col] = f2b(v);
                    else
                        ((float*)Out)[rr * 128 + col] = v;
                }
            }
        }
        buf ^= 1;
    }
}

// ---------------------------------------------------------------------------
extern "C" void kernel_launch(void* const* d_in, const int* in_sizes, int n_in,
                              void* d_out, int out_size, void* d_ws, size_t ws_size,
                              hipStream_t stream) {
    const float* x   = (const float*)d_in[0];
    const int*   eix = (const int*)d_in[1];
    const float* W1l = (const float*)d_in[2];
    const float* b1  = (const float*)d_in[3];
    const float* W1r = (const float*)d_in[4];
    const float* W2l = (const float*)d_in[5];
    const float* b2  = (const float*)d_in[6];
    const float* W2r = (const float*)d_in[7];
    float* out = (float*)d_out;

    int N = in_sizes[0] / 128;
    int E = in_sizes[1] / 2;
    if (N <= 0 || E <= 0) return;
    int nb1 = (N + (1 << BSH1) - 1) >> BSH1;

    char* ws = (char*)d_ws;
    size_t o = 0;
    auto alloc = [&](size_t bytes) -> void* {
        o = (o + 255) & ~(size_t)255;
        void* p = ws + o;
        o += bytes;
        return p;
    };
    int*            flag   = (int*)alloc(4);
    int*            bcnt   = (int*)alloc((size_t)nb1 * 4);
    int*            boff   = (int*)alloc(((size_t)nb1 + 1) * 4);
    int*            bcur   = (int*)alloc((size_t)nb1 * 4);
    int*            off    = (int*)alloc(((size_t)N + 1) * 4);
    int*            csr    = (int*)alloc((size_t)E * 4);
    unsigned short* xb     = (unsigned short*)alloc((size_t)N * 128 * 2);
    unsigned short* meanb  = (unsigned short*)alloc((size_t)N * 128 * 2);
    unsigned short* hb     = (unsigned short*)alloc((size_t)N * 128 * 2);
    bool full = (o <= ws_size);   // room for bf16 h?
    // pairs aliases meanb: dead before spmm writes meanb (needs E*4 <= N*256B)
    unsigned* pairs = (unsigned*)meanb;

    (void)hipFuncSetAttribute((const void*)gemm_mfma_kernel<0, 0>,
                              hipFuncAttributeMaxDynamicSharedMemorySize, GEMM_LDS);
    (void)hipFuncSetAttribute((const void*)gemm_mfma_kernel<0, 1>,
                              hipFuncAttributeMaxDynamicSharedMemorySize, GEMM_LDS);
    (void)hipFuncSetAttribute((const void*)gemm_mfma_kernel<0, 2>,
                              hipFuncAttributeMaxDynamicSharedMemorySize, GEMM_LDS);
    (void)hipFuncSetAttribute((const void*)gemm_mfma_kernel<1, 2>,
                              hipFuncAttributeMaxDynamicSharedMemorySize, GEMM_LDS);

    hipMemsetAsync(bcnt, 0, (size_t)nb1 * 4, stream);

    // CSR build: detect -> (cvt || coarse count) -> scan -> scatter -> fine sort
    detect_kernel<<<1, 256, 0, stream>>>(eix, in_sizes[1], flag);
    size_t cnt_lds = (size_t)nb1 * 4;
    cvt_count_kernel<<<2048 + 256, 256, cnt_lds, stream>>>(x, xb, N * 32,
                                                           eix, flag, bcnt, E, nb1, 2048);
    scan_kernel<<<1, 1024, 0, stream>>>(bcnt, boff, bcur, nb1);
    int nchunks = (E + CHUNK - 1) / CHUNK;
    int sgrid = nchunks < 2048 ? nchunks : 2048;
    coarse_scatter_kernel<<<sgrid, 256, 2 * cnt_lds, stream>>>(eix, flag, bcur, pairs, E, nb1);
    fine_csr_kernel<<<nb1, 256, 0, stream>>>(pairs, boff, off, csr, N, nb1, E);

    int spmm_grid = (N + 3) / 4;
    int ntiles = (N + 63) / 64;
    int ggrid = ntiles < 512 ? ntiles : 512;

    // layer 1
    spmm_mean_kernel<1><<<spmm_grid, 256, 0, stream>>>(xb, off, csr, (unsigned*)meanb, N);
    if (full) {
        gemm_mfma_kernel<0, 1><<<ggrid, 512, GEMM_LDS, stream>>>(
            meanb, xb, W1l, W1r, b1, hb, N, ntiles);
        spmm_mean_kernel<1><<<spmm_grid, 256, 0, stream>>>(hb, off, csr, (unsigned*)meanb, N);
        gemm_mfma_kernel<0, 2><<<ggrid, 512, GEMM_LDS, stream>>>(
            meanb, hb, W2l, W2r, b2, out, N, ntiles);
    } else {
        gemm_mfma_kernel<0, 0><<<ggrid, 512, GEMM_LDS, stream>>>(
            meanb, xb, W1l, W1r, b1, out, N, ntiles);
        spmm_mean_kernel<0><<<spmm_grid, 256, 0, stream>>>(out, off, csr, (unsigned*)meanb, N);
        gemm_mfma_kernel<1, 2><<<ggrid, 512, GEMM_LDS, stream>>>(
            meanb, out, W2l, W2r, b2, out, N, ntiles);
    }
}

// Round 10
// 250.952 us; speedup vs baseline: 1.0769x; 1.0189x over previous
//
#include <hip/hip_runtime.h>

// ---------------------------------------------------------------------------
// GraphSAGE 2-layer forward, MI355X (gfx950)
//   h   = relu(mean_agg(x) @ W1l + b1 + x @ W1r)
//   out =      mean_agg(h) @ W2l + b2 + h @ W2r
// R10: fine_csr v2 (bucket pairs + csr output staged in LDS, coalesced
// writeback; 196 blocks have whole CUs so LDS is free); coarse_scatter caches
// src+dst in regs. spmm (at 6.3TB/s logical = copy ceiling) & GEMM frozen.
// ---------------------------------------------------------------------------

typedef __attribute__((ext_vector_type(8))) short short8;
typedef __attribute__((ext_vector_type(4))) float floatx4;
typedef __attribute__((ext_vector_type(4))) unsigned short ushort4v;

#define BSH1 9                     // coarse bucket = 512 consecutive dst nodes
#define CHUNK 2048                 // edges per chunk (coarse scatter)
#define FINE_CAP 12288             // max bucket edges staged in LDS (48KB x2)
// packed pair: src in bits[0:23), dst&511 in bits[23:32). requires N < 2^23

__device__ inline unsigned short f2b(float f) {  // f32 -> bf16 (RNE)
    unsigned u = __builtin_bit_cast(unsigned, f);
    return (unsigned short)((u + 0x7FFFu + ((u >> 16) & 1u)) >> 16);
}
__device__ inline float blo(unsigned v) { return __builtin_bit_cast(float, v << 16); }
__device__ inline float bhi(unsigned v) { return __builtin_bit_cast(float, v & 0xffff0000u); }

// ---- edge layout detection (int64 vs int32 buffer) ------------------------
__global__ void detect_kernel(const int* __restrict__ e32, int nelem, int* flag) {
    __shared__ int bad;
    if (threadIdx.x == 0) bad = 0;
    __syncthreads();
    int half = nelem >> 1;  // = E
    int viol = 0;
    for (int i = threadIdx.x; i < 4096; i += blockDim.x) {
        long long k = ((long long)i * half) / 4096;
        if (e32[2 * k + 1] != 0) viol++;   // int64 => hi words all 0
    }
    if (viol) atomicAdd(&bad, viol);
    __syncthreads();
    if (threadIdx.x == 0) flag[0] = (bad == 0) ? 1 : 0;  // 1 = int64 layout
}

__device__ inline void decode_edge(const int* e32, bool is64, int E, int i, int& s, int& d) {
    if (is64) { s = e32[2 * (long long)i]; d = e32[2 * ((long long)E + i)]; }
    else      { s = e32[i];                d = e32[E + i]; }
}

// ---- fused: x->bf16 convert (blocks [0,cvtB)) + coarse count (rest) -------
__global__ __launch_bounds__(256) void cvt_count_kernel(const float* __restrict__ xin,
                                                        unsigned short* __restrict__ xb, int n4,
                                                        const int* __restrict__ e32,
                                                        const int* __restrict__ flag,
                                                        int* __restrict__ bcnt,
                                                        int E, int nb1, int cvtB) {
    if ((int)blockIdx.x < cvtB) {
        int stride = cvtB * 256;
        for (int i = blockIdx.x * 256 + threadIdx.x; i < n4; i += stride) {
            float4 v = ((const float4*)xin)[i];
            ushort4v o;
            o[0] = f2b(v.x); o[1] = f2b(v.y); o[2] = f2b(v.z); o[3] = f2b(v.w);
            ((ushort4v*)xb)[i] = o;
        }
    } else {
        extern __shared__ int lh[];
        for (int i = threadIdx.x; i < nb1; i += 256) lh[i] = 0;
        __syncthreads();
        bool is64 = flag[0] != 0;
        int cb = gridDim.x - cvtB;
        int stride = cb * 256;
        for (int i = (blockIdx.x - cvtB) * 256 + threadIdx.x; i < E; i += stride) {
            int d = is64 ? e32[2 * ((long long)E + i)] : e32[E + i];
            atomicAdd(&lh[d >> BSH1], 1);
        }
        __syncthreads();
        for (int i = threadIdx.x; i < nb1; i += 256) {
            int c = lh[i];
            if (c) atomicAdd(&bcnt[i], c);
        }
    }
}

// ---- exclusive scan (single block) ----------------------------------------
__global__ __launch_bounds__(1024) void scan_kernel(const int* __restrict__ deg,
                                                    int* __restrict__ off,
                                                    int* __restrict__ cursor, int N) {
    __shared__ int wsum[16];
    __shared__ int s_carry;
    int t = threadIdx.x;
    int lane = t & 63, w = t >> 6;
    if (t == 0) s_carry = 0;
    __syncthreads();
    for (int base = 0; base < N; base += 1024) {
        int i = base + t;
        int v = (i < N) ? deg[i] : 0;
        int sc = v;
        #pragma unroll
        for (int o = 1; o < 64; o <<= 1) {
            int u = __shfl_up(sc, o, 64);
            if (lane >= o) sc += u;
        }
        if (lane == 63) wsum[w] = sc;
        __syncthreads();
        int woff = 0;
        for (int j = 0; j < w; ++j) woff += wsum[j];
        int c = s_carry;
        int excl = c + woff + (sc - v);
        if (i < N) { off[i] = excl; cursor[i] = excl; }
        __syncthreads();
        if (t == 1023) s_carry = c + woff + sc;
        __syncthreads();
    }
    if (t == 0) off[N] = s_carry;
}

// ---- coarse scatter: src+dst cached in regs, one reservation per bucket ---
__global__ __launch_bounds__(256) void coarse_scatter_kernel(const int* __restrict__ e32,
                                                             const int* __restrict__ flag,
                                                             int* __restrict__ bcur,
                                                             unsigned* __restrict__ pairs,
                                                             int E, int nb1) {
    extern __shared__ int lh[];            // [nb1] cursor/hist + [nb1] base
    int t = threadIdx.x;
    bool is64 = flag[0] != 0;
    int nchunks = (E + CHUNK - 1) / CHUNK;
    for (int ch = blockIdx.x; ch < nchunks; ch += gridDim.x) {
        int e0 = ch * CHUNK;
        int e1 = min(e0 + CHUNK, E);
        for (int i = t; i < nb1; i += 256) lh[i] = 0;
        __syncthreads();
        int dreg[CHUNK / 256], sreg[CHUNK / 256];
        #pragma unroll
        for (int j = 0; j < CHUNK / 256; ++j) {
            int i = e0 + j * 256 + t;
            int s = 0, d = -1;
            if (i < e1) decode_edge(e32, is64, E, i, s, d);
            dreg[j] = d; sreg[j] = s;
            if (d >= 0) atomicAdd(&lh[d >> BSH1], 1);
        }
        __syncthreads();
        for (int i = t; i < nb1; i += 256) {
            int c = lh[i];
            lh[nb1 + i] = c ? atomicAdd(&bcur[i], c) : 0;   // global reservation
            lh[i] = 0;                                      // reuse as local cursor
        }
        __syncthreads();
        #pragma unroll
        for (int j = 0; j < CHUNK / 256; ++j) {
            int d = dreg[j];
            if (d >= 0) {
                int k = d >> BSH1;
                int r = atomicAdd(&lh[k], 1);
                pairs[lh[nb1 + k] + r] =
                    (unsigned)sreg[j] | ((unsigned)(d & ((1 << BSH1) - 1)) << 23);
            }
        }
        __syncthreads();
    }
}

// ---- fine CSR build v2: bucket pairs + csr staged in LDS ------------------
// one block per coarse bucket; ~196 blocks on 256 CUs -> whole CU per block,
// LDS is free. Stage pairs (coalesced read), hist/scan/scatter in LDS, then
// coalesced csr writeback. Fallback to global path if bucket > FINE_CAP.
__global__ __launch_bounds__(256) void fine_csr_kernel(const unsigned* __restrict__ pairs,
                                                       const int* __restrict__ boff,
                                                       int* __restrict__ off,
                                                       int* __restrict__ csr,
                                                       int N, int nb1, int E) {
    __shared__ int ldeg[512], loff[512];
    __shared__ int wsum[4];
    extern __shared__ unsigned lbuf[];      // [FINE_CAP] pairs + [FINE_CAP] csr
    unsigned* lpair = lbuf;
    unsigned* lcsr  = lbuf + FINE_CAP;
    int b = blockIdx.x;
    if (b >= nb1) return;
    int t = threadIdx.x;
    int p0 = boff[b], p1 = boff[b + 1];
    int nloc = p1 - p0;
    bool inlds = (nloc <= FINE_CAP);
    int base = b << BSH1;
    ldeg[2 * t] = 0; ldeg[2 * t + 1] = 0;
    __syncthreads();
    if (inlds) {
        for (int i = t; i < nloc; i += 256) {
            unsigned e = pairs[p0 + i];
            lpair[i] = e;
            atomicAdd(&ldeg[e >> 23], 1);
        }
    } else {
        for (int i = p0 + t; i < p1; i += 256) atomicAdd(&ldeg[pairs[i] >> 23], 1);
    }
    __syncthreads();
    // exclusive scan of 512 entries with 256 threads
    {
        int lane = t & 63, w = t >> 6;
        int v0 = ldeg[2 * t], v1 = ldeg[2 * t + 1];
        int v = v0 + v1, sc = v;
        #pragma unroll
        for (int o = 1; o < 64; o <<= 1) {
            int u = __shfl_up(sc, o, 64);
            if (lane >= o) sc += u;
        }
        if (lane == 63) wsum[w] = sc;
        __syncthreads();
        int cross = 0;
        for (int j = 0; j < w; ++j) cross += wsum[j];
        int ex = cross + sc - v;
        loff[2 * t] = ex;
        loff[2 * t + 1] = ex + v0;
        int d0 = base + 2 * t, d1 = d0 + 1;
        if (d0 < N) off[d0] = p0 + ex;
        if (d1 < N) off[d1] = p0 + ex + v0;
    }
    __syncthreads();
    ldeg[2 * t] = 0; ldeg[2 * t + 1] = 0;   // reuse as cursors
    __syncthreads();
    if (inlds) {
        for (int i = t; i < nloc; i += 256) {
            unsigned e = lpair[i];
            int dl = e >> 23;
            int r = atomicAdd(&ldeg[dl], 1);
            lcsr[loff[dl] + r] = e & 0x7FFFFFu;
        }
        __syncthreads();
        for (int i = t; i < nloc; i += 256) csr[p0 + i] = (int)lcsr[i];   // coalesced
    } else {
        for (int i = p0 + t; i < p1; i += 256) {
            unsigned e = pairs[i];
            int dl = e >> 23;
            int r = atomicAdd(&ldeg[dl], 1);
            csr[p0 + loff[dl] + r] = (int)(e & 0x7FFFFFu);
        }
    }
    if (b == 0 && t == 0) off[N] = E;
}

// ---- SpMM mean: gather rows of X (bf16 or f32), write bf16 mean -----------
// one wave per node; unroll 8 for memory-level parallelism (R6 winner form)
template<int BF16IN>
__global__ __launch_bounds__(256) void spmm_mean_kernel(const void* __restrict__ Xv,
                                                        const int* __restrict__ off,
                                                        const int* __restrict__ csr,
                                                        unsigned* __restrict__ outb, int N) {
    int wid = blockIdx.x * 4 + (threadIdx.x >> 6);
    int lane = threadIdx.x & 63;
    if (wid >= N) return;
    int b0 = off[wid], b1 = off[wid + 1];
    float ax = 0.f, ay = 0.f;
    int i = b0;
    if (BF16IN) {
        const unsigned* X = (const unsigned*)Xv;   // row = 64 uints (128 bf16)
        for (; i + 7 < b1; i += 8) {
            int s0 = csr[i],     s1 = csr[i + 1], s2 = csr[i + 2], s3 = csr[i + 3];
            int s4 = csr[i + 4], s5 = csr[i + 5], s6 = csr[i + 6], s7 = csr[i + 7];
            unsigned v0 = X[(long long)s0 * 64 + lane];
            unsigned v1 = X[(long long)s1 * 64 + lane];
            unsigned v2 = X[(long long)s2 * 64 + lane];
            unsigned v3 = X[(long long)s3 * 64 + lane];
            unsigned v4 = X[(long long)s4 * 64 + lane];
            unsigned v5 = X[(long long)s5 * 64 + lane];
            unsigned v6 = X[(long long)s6 * 64 + lane];
            unsigned v7 = X[(long long)s7 * 64 + lane];
            ax += (blo(v0) + blo(v1)) + (blo(v2) + blo(v3)) +
                  ((blo(v4) + blo(v5)) + (blo(v6) + blo(v7)));
            ay += (bhi(v0) + bhi(v1)) + (bhi(v2) + bhi(v3)) +
                  ((bhi(v4) + bhi(v5)) + (bhi(v6) + bhi(v7)));
        }
        for (; i + 3 < b1; i += 4) {
            int s0 = csr[i], s1 = csr[i + 1], s2 = csr[i + 2], s3 = csr[i + 3];
            unsigned v0 = X[(long long)s0 * 64 + lane];
            unsigned v1 = X[(long long)s1 * 64 + lane];
            unsigned v2 = X[(long long)s2 * 64 + lane];
            unsigned v3 = X[(long long)s3 * 64 + lane];
            ax += blo(v0) + blo(v1) + blo(v2) + blo(v3);
            ay += bhi(v0) + bhi(v1) + bhi(v2) + bhi(v3);
        }
        for (; i < b1; ++i) {
            unsigned v = X[(long long)csr[i] * 64 + lane];
            ax += blo(v); ay += bhi(v);
        }
    } else {
        const float2* X = (const float2*)Xv;
        for (; i + 3 < b1; i += 4) {
            int s0 = csr[i], s1 = csr[i + 1], s2 = csr[i + 2], s3 = csr[i + 3];
            float2 v0 = X[(long long)s0 * 64 + lane];
            float2 v1 = X[(long long)s1 * 64 + lane];
            float2 v2 = X[(long long)s2 * 64 + lane];
            float2 v3 = X[(long long)s3 * 64 + lane];
            ax += v0.x + v1.x + v2.x + v3.x;
            ay += v0.y + v1.y + v2.y + v3.y;
        }
        for (; i < b1; ++i) {
            float2 v = X[(long long)csr[i] * 64 + lane];
            ax += v.x; ay += v.y;
        }
    }
    int dgr = b1 - b0;
    float inv = (dgr > 0) ? 1.0f / (float)dgr : 0.0f;
    unsigned pack = (unsigned)f2b(ax * inv) | ((unsigned)f2b(ay * inv) << 16);
    outb[(long long)wid * 64 + lane] = pack;
}

// ---- MFMA GEMM v2: Out[r][c] = bias[c] + Am[r]@W[0:128] + Ax[r]@W[128:256]
// 512 thr / 8 waves; W staged via LDS ONCE -> B-frags in regs; same LDS then
// reused as A double-buffer. 69.6KB -> 2 blocks/CU.
#define APAD       136
#define WT_STRIDE  264
#define APANEL2    (64 * APAD)
#define ABUF2      (2 * APANEL2)
#define GEMM_LDS   (2 * ABUF2 * 2)           // 69632 B

template<int XF32, int OUTMODE>
__global__ __launch_bounds__(512, 4) void gemm_mfma_kernel(
    const unsigned short* __restrict__ Am, const void* __restrict__ Ax,
    const float* __restrict__ Wl, const float* __restrict__ Wr,
    const float* __restrict__ bias, void* __restrict__ Out,
    int N, int ntiles)
{
    extern __shared__ unsigned short lds[];
    int t = threadIdx.x;
    int lane = t & 63, wv = t >> 6;
    int lm = lane & 15, q = lane >> 4;
    int c0 = wv * 16;

    for (int it = 0; it < 32; ++it) {
        int n = t & 127;
        int kp = it * 4 + (t >> 7);
        int k = 2 * kp;
        const float* Wsrc = (k < 128) ? (Wl + k * 128) : (Wr + (k - 128) * 128);
        unsigned pack = (unsigned)f2b(Wsrc[n]) | ((unsigned)f2b(Wsrc[128 + n]) << 16);
        *(unsigned*)(lds + n * WT_STRIDE + k) = pack;
    }
    __syncthreads();
    short8 breg[8];
    #pragma unroll
    for (int ks = 0; ks < 8; ++ks)
        breg[ks] = *(const short8*)(lds + (c0 + lm) * WT_STRIDE + ks * 32 + q * 8);
    __syncthreads();   // B-frag reads done before LDS reuse

    float bias0 = bias[c0 + lm];

    short8 pm[2], px[2];
    auto prefetch = [&](int tl) {
        long long row0 = (long long)tl * 64;
        #pragma unroll
        for (int j = 0; j < 2; ++j) {
            int cid = j * 512 + t;
            int row = cid >> 4, cp = cid & 15;
            long long gr = row0 + row;
            bool ok = gr < (long long)N;
            pm[j] = ok ? *(const short8*)(Am + gr * 128 + cp * 8) : (short8)0;
            if (XF32) {
                short8 s = (short8)0;
                if (ok) {
                    const float* xp = (const float*)Ax + gr * 128 + cp * 8;
                    floatx4 u0 = *(const floatx4*)xp;
                    floatx4 u1 = *(const floatx4*)(xp + 4);
                    s[0] = (short)f2b(u0[0]); s[1] = (short)f2b(u0[1]);
                    s[2] = (short)f2b(u0[2]); s[3] = (short)f2b(u0[3]);
                    s[4] = (short)f2b(u1[0]); s[5] = (short)f2b(u1[1]);
                    s[6] = (short)f2b(u1[2]); s[7] = (short)f2b(u1[3]);
                }
                px[j] = s;
            } else {
                px[j] = ok ? *(const short8*)((const unsigned short*)Ax + gr * 128 + cp * 8)
                           : (short8)0;
            }
        }
    };

    int tile = blockIdx.x;
    if (tile < ntiles) prefetch(tile);
    int buf = 0;
    for (; tile < ntiles; tile += gridDim.x) {
        unsigned short* A = lds + buf * ABUF2;
        __syncthreads();
        #pragma unroll
        for (int j = 0; j < 2; ++j) {
            int cid = j * 512 + t;
            int row = cid >> 4, cp = cid & 15;
            *(short8*)(A + row * APAD + cp * 8) = pm[j];
            *(short8*)(A + APANEL2 + row * APAD + cp * 8) = px[j];
        }
        __syncthreads();
        int nt = tile + gridDim.x;
        if (nt < ntiles) prefetch(nt);

        floatx4 acc[4];
        #pragma unroll
        for (int rf = 0; rf < 4; ++rf) acc[rf] = (floatx4)bias0;
        #pragma unroll
        for (int ks = 0; ks < 8; ++ks) {
            const unsigned short* P = A + (ks >= 4 ? APANEL2 : 0);
            int k0 = (ks & 3) * 32 + q * 8;
            #pragma unroll
            for (int rf = 0; rf < 4; ++rf) {
                short8 a = *(const short8*)(P + (rf * 16 + lm) * APAD + k0);
                acc[rf] = __builtin_amdgcn_mfma_f32_16x16x32_bf16(a, breg[ks], acc[rf], 0, 0, 0);
            }
        }

        long long r0 = (long long)tile * 64;
        int col = c0 + lm;
        #pragma unroll
        for (int rf = 0; rf < 4; ++rf) {
            #pragma unroll
            for (int rg = 0; rg < 4; ++rg) {
                long long rr = r0 + rf * 16 + q * 4 + rg;
                if (rr < (long long)N) {
                    float v = acc[rf][rg];
                    if (OUTMODE != 2) v = fmaxf(v, 0.f);
                    if (OUTMODE == 1)
                        ((unsigned short*)Out)[rr * 128 + col] = f2b(v);
                    else
                        ((float*)Out)[rr * 128 + col] = v;
                }
            }
        }
        buf ^= 1;
    }
}

// ---------------------------------------------------------------------------
extern "C" void kernel_launch(void* const* d_in, const int* in_sizes, int n_in,
                              void* d_out, int out_size, void* d_ws, size_t ws_size,
                              hipStream_t stream) {
    const float* x   = (const float*)d_in[0];
    const int*   eix = (const int*)d_in[1];
    const float* W1l = (const float*)d_in[2];
    const float* b1  = (const float*)d_in[3];
    const float* W1r = (const float*)d_in[4];
    const float* W2l = (const float*)d_in[5];
    const float* b2  = (const float*)d_in[6];
    const float* W2r = (const float*)d_in[7];
    float* out = (float*)d_out;

    int N = in_sizes[0] / 128;
    int E = in_sizes[1] / 2;
    if (N <= 0 || E <= 0) return;
    int nb1 = (N + (1 << BSH1) - 1) >> BSH1;

    char* ws = (char*)d_ws;
    size_t o = 0;
    auto alloc = [&](size_t bytes) -> void* {
        o = (o + 255) & ~(size_t)255;
        void* p = ws + o;
        o += bytes;
        return p;
    };
    int*            flag   = (int*)alloc(4);
    int*            bcnt   = (int*)alloc((size_t)nb1 * 4);
    int*            boff   = (int*)alloc(((size_t)nb1 + 1) * 4);
    int*            bcur   = (int*)alloc((size_t)nb1 * 4);
    int*            off    = (int*)alloc(((size_t)N + 1) * 4);
    int*            csr    = (int*)alloc((size_t)E * 4);
    unsigned short* xb     = (unsigned short*)alloc((size_t)N * 128 * 2);
    unsigned short* meanb  = (unsigned short*)alloc((size_t)N * 128 * 2);
    unsigned short* hb     = (unsigned short*)alloc((size_t)N * 128 * 2);
    bool full = (o <= ws_size);   // room for bf16 h?
    unsigned* pairs = (unsigned*)meanb;   // aliases meanb (dead until spmm)

    size_t fine_lds = (size_t)2 * FINE_CAP * 4;   // 98304 B
    (void)hipFuncSetAttribute((const void*)fine_csr_kernel,
                              hipFuncAttributeMaxDynamicSharedMemorySize, (int)fine_lds);
    (void)hipFuncSetAttribute((const void*)gemm_mfma_kernel<0, 0>,
                              hipFuncAttributeMaxDynamicSharedMemorySize, GEMM_LDS);
    (void)hipFuncSetAttribute((const void*)gemm_mfma_kernel<0, 1>,
                              hipFuncAttributeMaxDynamicSharedMemorySize, GEMM_LDS);
    (void)hipFuncSetAttribute((const void*)gemm_mfma_kernel<0, 2>,
                              hipFuncAttributeMaxDynamicSharedMemorySize, GEMM_LDS);
    (void)hipFuncSetAttribute((const void*)gemm_mfma_kernel<1, 2>,
                              hipFuncAttributeMaxDynamicSharedMemorySize, GEMM_LDS);

    hipMemsetAsync(bcnt, 0, (size_t)nb1 * 4, stream);

    // CSR build: detect -> (cvt || coarse count) -> scan -> scatter -> fine sort
    detect_kernel<<<1, 256, 0, stream>>>(eix, in_sizes[1], flag);
    size_t cnt_lds = (size_t)nb1 * 4;
    cvt_count_kernel<<<2048 + 256, 256, cnt_lds, stream>>>(x, xb, N * 32,
                                                           eix, flag, bcnt, E, nb1, 2048);
    scan_kernel<<<1, 1024, 0, stream>>>(bcnt, boff, bcur, nb1);
    int nchunks = (E + CHUNK - 1) / CHUNK;
    int sgrid = nchunks < 2048 ? nchunks : 2048;
    coarse_scatter_kernel<<<sgrid, 256, 2 * cnt_lds, stream>>>(eix, flag, bcur, pairs, E, nb1);
    fine_csr_kernel<<<nb1, 256, fine_lds, stream>>>(pairs, boff, off, csr, N, nb1, E);

    int spmm_grid = (N + 3) / 4;
    int ntiles = (N + 63) / 64;
    int ggrid = ntiles < 512 ? ntiles : 512;

    // layer 1
    spmm_mean_kernel<1><<<spmm_grid, 256, 0, stream>>>(xb, off, csr, (unsigned*)meanb, N);
    if (full) {
        gemm_mfma_kernel<0, 1><<<ggrid, 512, GEMM_LDS, stream>>>(
            meanb, xb, W1l, W1r, b1, hb, N, ntiles);
        spmm_mean_kernel<1><<<spmm_grid, 256, 0, stream>>>(hb, off, csr, (unsigned*)meanb, N);
        gemm_mfma_kernel<0, 2><<<ggrid, 512, GEMM_LDS, stream>>>(
            meanb, hb, W2l, W2r, b2, out, N, ntiles);
    } else {
        gemm_mfma_kernel<0, 0><<<ggrid, 512, GEMM_LDS, stream>>>(
            meanb, xb, W1l, W1r, b1, out, N, ntiles);
        spmm_mean_kernel<0><<<spmm_grid, 256, 0, stream>>>(out, off, csr, (unsigned*)meanb, N);
        gemm_mfma_kernel<1, 2><<<ggrid, 512, GEMM_LDS, stream>>>(
            meanb, out, W2l, W2r, b2, out, N, ntiles);
    }
}